// Round 6
// baseline (161.317 us; speedup 1.0000x reference)
//
#include <hip/hip_runtime.h>
#include <math.h>

#define DIM 256
#define KCODES 1024
#define NCHUNK 16          // 1024 codes / 64 per chunk
#define CHUNK_BYTES 32768  // 64 codes x 256 dims x 2B (fragment order)
#define BM 128             // rows per block

typedef __attribute__((ext_vector_type(8))) short bf16x8;
typedef __attribute__((ext_vector_type(4))) float f32x4;
typedef __attribute__((ext_vector_type(4))) unsigned short u16x4;

__device__ inline unsigned short f2bf(float x) {
  union { float f; unsigned u; } v;
  v.f = x;
  return (unsigned short)((v.u + 0x8000u) >> 16);
}

// ---------------------------------------------------------------------------
// Prep: enormh[k] = -0.5*||e_k||^2, codebook in MFMA B-fragment order:
// byte = ((k>>4)*8 + ks)*1024 + (lk*16 + (k&15))*16 + (t&1)*8
// ---------------------------------------------------------------------------
__global__ __launch_bounds__(64) void vq_prep_kernel(
    const float* __restrict__ E, float* __restrict__ enormh,
    unsigned short* __restrict__ Ef) {
  const int k = blockIdx.x;   // code
  const int t = threadIdx.x;  // dims 4t..4t+3
  const float4 v = *reinterpret_cast<const float4*>(&E[k * DIM + t * 4]);
  u16x4 o;
  o[0] = f2bf(v.x); o[1] = f2bf(v.y); o[2] = f2bf(v.z); o[3] = f2bf(v.w);
  const int ks = t >> 3;
  const int lk = (t >> 1) & 3;
  const size_t byte = (size_t)(((k >> 4) * 8 + ks) * 1024) +
                      (size_t)((lk * 16 + (k & 15)) * 16) +
                      (size_t)((t & 1) * 8);
  *reinterpret_cast<u16x4*>(reinterpret_cast<char*>(Ef) + byte) = o;
  float s = v.x * v.x + v.y * v.y + v.z * v.z + v.w * v.w;
#pragma unroll
  for (int off = 32; off >= 1; off >>= 1) s += __shfl_down(s, off);
  if (t == 0) enormh[k] = -0.5f * s;
}

// ---------------------------------------------------------------------------
// Fused main: 128 rows/block, 512 threads (8 waves = 2 row-groups x 4
// code-tiles). A register-resident bf16; B double-buffered via
// global_load_lds, one barrier per 64-code chunk, fully unrolled.
// __launch_bounds__(512, 1): 8-wave workgroup -> 2 waves/SIMD -> 256-VGPR
// cap; min-waves=1 releases the default 128-reg occupancy target so Afrag
// (128 VGPRs) + acc/argmin state (~100) stay in registers. NO SPILL.
// ---------------------------------------------------------------------------
__global__ __launch_bounds__(512, 1) void vq_fused_kernel(
    const float* __restrict__ X, const float* __restrict__ E,
    const unsigned short* __restrict__ Ef, const float* __restrict__ enormh,
    float* __restrict__ outq, float* __restrict__ partials) {
  __shared__ char Bb[2][CHUNK_BYTES];  // 64 KB
  __shared__ float fval_s[4][BM];      // per-ct row maxima
  __shared__ int fidx_s[4][BM];
  __shared__ int idxs[BM];
  __shared__ float lred[8];

  const int tid = threadIdx.x;
  const int w = tid >> 6;
  const int lane = tid & 63;
  const int lr = lane & 15;
  const int lk = lane >> 4;
  const int g = w >> 2;   // row-group (0/1)
  const int ct = w & 3;   // code-tile within chunk
  const int row0 = blockIdx.x * BM + g * 64;

  // ---- issue chunk-0 staging first (latency overlaps A setup)
#pragma unroll
  for (int i = 0; i < 4; ++i) {
    const int o = i * 8192 + tid * 16;
    __builtin_amdgcn_global_load_lds(
        (const __attribute__((address_space(1))) unsigned int*)(
            reinterpret_cast<const char*>(Ef) + o),
        (__attribute__((address_space(3))) unsigned int*)(&Bb[0][o]), 16, 0, 0);
  }

  // ---- A: 64 rows x 256 dims per wave, fp32 -> bf16 fragments in registers
  bf16x8 Afrag[4][8];
#pragma unroll
  for (int mt = 0; mt < 4; ++mt) {
    const float* xrow = &X[(size_t)(row0 + mt * 16 + lr) * DIM];
#pragma unroll
    for (int ks = 0; ks < 8; ++ks) {
      const int k0 = ks * 32 + lk * 8;
      const float4 a = *reinterpret_cast<const float4*>(&xrow[k0]);
      const float4 b = *reinterpret_cast<const float4*>(&xrow[k0 + 4]);
      bf16x8 f;
      f[0] = (short)f2bf(a.x); f[1] = (short)f2bf(a.y);
      f[2] = (short)f2bf(a.z); f[3] = (short)f2bf(a.w);
      f[4] = (short)f2bf(b.x); f[5] = (short)f2bf(b.y);
      f[6] = (short)f2bf(b.z); f[7] = (short)f2bf(b.w);
      Afrag[mt][ks] = f;
    }
  }

  // per-lane -||e||^2/2 for this lane's code in each chunk (static index)
  float enh[NCHUNK];
#pragma unroll
  for (int t = 0; t < NCHUNK; ++t) enh[t] = enormh[t * 64 + ct * 16 + lr];

  float maxv[16];
  int mini[16];
#pragma unroll
  for (int i = 0; i < 16; ++i) { maxv[i] = -INFINITY; mini[i] = 0; }

#pragma unroll
  for (int t = 0; t < NCHUNK; ++t) {
    __syncthreads();  // drains vmcnt -> chunk t resident in Bb[t&1]
    if (t + 1 < NCHUNK) {  // issue chunk t+1 into the other buffer
      const char* src =
          reinterpret_cast<const char*>(Ef) + (size_t)(t + 1) * CHUNK_BYTES;
      char* dst = Bb[(t + 1) & 1];
#pragma unroll
      for (int i = 0; i < 4; ++i) {
        const int o = i * 8192 + tid * 16;
        __builtin_amdgcn_global_load_lds(
            (const __attribute__((address_space(1))) unsigned int*)(src + o),
            (__attribute__((address_space(3))) unsigned int*)(dst + o), 16, 0,
            0);
      }
    }
    const float e = enh[t];
    f32x4 acc[4];
#pragma unroll
    for (int mt = 0; mt < 4; ++mt) {
      acc[mt][0] = e; acc[mt][1] = e; acc[mt][2] = e; acc[mt][3] = e;
    }
#pragma unroll
    for (int ks = 0; ks < 8; ++ks) {
      const bf16x8 bf = *reinterpret_cast<const bf16x8*>(
          &Bb[t & 1][ct * 8192 + ks * 1024 + lane * 16]);
#pragma unroll
      for (int mt = 0; mt < 4; ++mt)
        acc[mt] = __builtin_amdgcn_mfma_f32_16x16x32_bf16(Afrag[mt][ks], bf,
                                                          acc[mt], 0, 0, 0);
    }
    const int code = t * 64 + ct * 16 + lr;
#pragma unroll
    for (int mt = 0; mt < 4; ++mt)
#pragma unroll
      for (int r = 0; r < 4; ++r) {
        const float s = acc[mt][r];
        const int ri = mt * 4 + r;  // row mt*16 + lk*4 + r
        if (s > maxv[ri]) { maxv[ri] = s; mini[ri] = code; }
      }
  }

  // reduce across the 16 code-lanes (lr); max score, tie -> lower code
#pragma unroll
  for (int off = 1; off < 16; off <<= 1) {
#pragma unroll
    for (int ri = 0; ri < 16; ++ri) {
      const float ov = __shfl_xor(maxv[ri], off);
      const int oi = __shfl_xor(mini[ri], off);
      if (ov > maxv[ri] || (ov == maxv[ri] && oi < mini[ri])) {
        maxv[ri] = ov; mini[ri] = oi;
      }
    }
  }
  if (lr == 0) {
#pragma unroll
    for (int mt = 0; mt < 4; ++mt)
#pragma unroll
      for (int r = 0; r < 4; ++r) {
        fval_s[ct][g * 64 + mt * 16 + lk * 4 + r] = maxv[mt * 4 + r];
        fidx_s[ct][g * 64 + mt * 16 + lk * 4 + r] = mini[mt * 4 + r];
      }
  }
  __syncthreads();
  if (tid < BM) {
    float bv = fval_s[0][tid];
    int bi = fidx_s[0][tid];
#pragma unroll
    for (int c = 1; c < 4; ++c) {
      const float v = fval_s[c][tid];
      const int i = fidx_s[c][tid];
      if (v > bv || (v == bv && i < bi)) { bv = v; bi = i; }
    }
    idxs[tid] = bi;
  }
  __syncthreads();

  // ---- fused epilogue: gather + STE + loss partial, exact fp32.
  // 4 threads per row, 64 dims each, coalesced float4.
  const int er = tid >> 2;  // row 0..127
  const int eq = tid & 3;
  const int code = idxs[er];
  const float* erow = &E[(size_t)code * DIM];
  const float* xrow = &X[(size_t)(blockIdx.x * BM + er) * DIM];
  float* orow = &outq[(size_t)(blockIdx.x * BM + er) * DIM];
  float lsum = 0.0f;
#pragma unroll
  for (int j = 0; j < 16; ++j) {
    const int d = j * 16 + eq * 4;
    const float4 e = *reinterpret_cast<const float4*>(&erow[d]);
    const float4 x = *reinterpret_cast<const float4*>(&xrow[d]);
    const float dx0 = e.x - x.x, dx1 = e.y - x.y;
    const float dx2 = e.z - x.z, dx3 = e.w - x.w;
    float4 o;
    o.x = x.x + dx0; o.y = x.y + dx1; o.z = x.z + dx2; o.w = x.w + dx3;
    *reinterpret_cast<float4*>(&orow[d]) = o;
    lsum += dx0 * dx0 + dx1 * dx1 + dx2 * dx2 + dx3 * dx3;
  }
#pragma unroll
  for (int off = 32; off >= 1; off >>= 1) lsum += __shfl_down(lsum, off);
  if (lane == 0) lred[w] = lsum;
  __syncthreads();
  if (tid == 0) {
    float s = 0.0f;
#pragma unroll
    for (int i = 0; i < 8; ++i) s += lred[i];
    partials[blockIdx.x] = s;
  }
}

// ---------------------------------------------------------------------------
// Deterministic loss reduction
// ---------------------------------------------------------------------------
__global__ __launch_bounds__(256) void vq_finalize_kernel(
    const float* __restrict__ partials, float* __restrict__ out_loss,
    int nparts, float inv_count) {
  const int tid = threadIdx.x;
  float s = 0.0f;
  for (int i = tid; i < nparts; i += 256) s += partials[i];
#pragma unroll
  for (int off = 32; off >= 1; off >>= 1) s += __shfl_down(s, off);
  __shared__ float w[4];
  if ((tid & 63) == 0) w[tid >> 6] = s;
  __syncthreads();
  if (tid == 0) {
    const float m = (w[0] + w[1] + w[2] + w[3]) * inv_count;
    out_loss[0] = m + 0.25f * m;  // q_latent + commitment * e_latent
  }
}

extern "C" void kernel_launch(void* const* d_in, const int* in_sizes, int n_in,
                              void* d_out, int out_size, void* d_ws,
                              size_t ws_size, hipStream_t stream) {
  const float* X = (const float*)d_in[0];  // [16,4096,256] fp32
  const float* E = (const float*)d_in[1];  // [1024,256] fp32
  float* out = (float*)d_out;              // [0]=loss, [1..]=quantized

  char* ws = (char*)d_ws;
  float* enormh = (float*)ws;                              // @0KB
  float* partials = (float*)(ws + 16 * 1024);              // @16KB
  unsigned short* Ef = (unsigned short*)(ws + 32 * 1024);  // @32KB (512KB)

  const int nrows = in_sizes[0] / DIM;  // 65536
  const int nb_main = nrows / BM;       // 512

  vq_prep_kernel<<<KCODES, 64, 0, stream>>>(E, enormh, Ef);
  vq_fused_kernel<<<nb_main, 512, 0, stream>>>(X, E, Ef, enormh, out + 1,
                                               partials);
  vq_finalize_kernel<<<1, 256, 0, stream>>>(partials, out, nb_main,
                                            1.0f / (float)in_sizes[0]);
}

// Round 7
// 116.504 us; speedup vs baseline: 1.3846x; 1.3846x over previous
//
#include <hip/hip_runtime.h>
#include <math.h>

#define DIM 256
#define KCODES 1024
#define NCHUNK 16          // 1024 codes / 64 per chunk
#define CHUNK_BYTES 32768  // 64 codes x 256 dims x 2B (fragment order)
#define BM 64              // rows per block

typedef __attribute__((ext_vector_type(8))) short bf16x8;
typedef __attribute__((ext_vector_type(4))) float f32x4;
typedef __attribute__((ext_vector_type(4))) unsigned short u16x4;

__device__ inline unsigned short f2bf(float x) {
  union { float f; unsigned u; } v;
  v.f = x;
  return (unsigned short)((v.u + 0x8000u) >> 16);
}

// ---------------------------------------------------------------------------
// Prep: enormh[k] = -0.5*||e_k||^2, codebook in MFMA B-fragment order:
// byte = ((k>>4)*8 + ks)*1024 + (lk*16 + (k&15))*16 + (t&1)*8
// ---------------------------------------------------------------------------
__global__ __launch_bounds__(64) void vq_prep_kernel(
    const float* __restrict__ E, float* __restrict__ enormh,
    unsigned short* __restrict__ Ef) {
  const int k = blockIdx.x;   // code
  const int t = threadIdx.x;  // dims 4t..4t+3
  const float4 v = *reinterpret_cast<const float4*>(&E[k * DIM + t * 4]);
  u16x4 o;
  o[0] = f2bf(v.x); o[1] = f2bf(v.y); o[2] = f2bf(v.z); o[3] = f2bf(v.w);
  const int ks = t >> 3;
  const int lk = (t >> 1) & 3;
  const size_t byte = (size_t)(((k >> 4) * 8 + ks) * 1024) +
                      (size_t)((lk * 16 + (k & 15)) * 16) +
                      (size_t)((t & 1) * 8);
  *reinterpret_cast<u16x4*>(reinterpret_cast<char*>(Ef) + byte) = o;
  float s = v.x * v.x + v.y * v.y + v.z * v.z + v.w * v.w;
#pragma unroll
  for (int off = 32; off >= 1; off >>= 1) s += __shfl_down(s, off);
  if (t == 0) enormh[k] = -0.5f * s;
}

// ---------------------------------------------------------------------------
// Fused main v7: 64 rows/block, 512 threads (8 waves = 2 row-groups x 4
// code-tiles -> EACH WAVE OWNS 32 ROWS). Afrag[2][8] = 64 VGPRs, total live
// ~120 <= 128-reg budget -> no spill by construction. B double-buffered via
// global_load_lds, one barrier per 64-code chunk, fully unrolled.
// ---------------------------------------------------------------------------
__global__ __launch_bounds__(512) void vq_fused_kernel(
    const float* __restrict__ X, const float* __restrict__ E,
    const unsigned short* __restrict__ Ef, const float* __restrict__ enormh,
    float* __restrict__ outq, float* __restrict__ partials) {
  __shared__ char Bb[2][CHUNK_BYTES];  // 64 KB
  __shared__ float fval_s[4][BM];      // per-code-tile row maxima
  __shared__ int fidx_s[4][BM];
  __shared__ int idxs[BM];
  __shared__ float lred[8];

  const int tid = threadIdx.x;
  const int w = tid >> 6;
  const int lane = tid & 63;
  const int lr = lane & 15;
  const int lk = lane >> 4;
  const int g = w >> 2;   // row-group (0/1): rows g*32 .. g*32+31
  const int ct = w & 3;   // code-tile within chunk (16 codes)
  const int row0 = blockIdx.x * BM;

  // ---- issue chunk-0 staging first (latency overlaps A setup)
#pragma unroll
  for (int i = 0; i < 4; ++i) {
    const int o = i * 8192 + tid * 16;
    __builtin_amdgcn_global_load_lds(
        (const __attribute__((address_space(1))) unsigned int*)(
            reinterpret_cast<const char*>(Ef) + o),
        (__attribute__((address_space(3))) unsigned int*)(&Bb[0][o]), 16, 0, 0);
  }

  // ---- A: 32 rows x 256 dims per wave, fp32 -> bf16 fragments (64 VGPRs)
  bf16x8 Afrag[2][8];
#pragma unroll
  for (int mt = 0; mt < 2; ++mt) {
    const float* xrow = &X[(size_t)(row0 + g * 32 + mt * 16 + lr) * DIM];
#pragma unroll
    for (int ks = 0; ks < 8; ++ks) {
      const int k0 = ks * 32 + lk * 8;
      const float4 a = *reinterpret_cast<const float4*>(&xrow[k0]);
      const float4 b = *reinterpret_cast<const float4*>(&xrow[k0 + 4]);
      bf16x8 f;
      f[0] = (short)f2bf(a.x); f[1] = (short)f2bf(a.y);
      f[2] = (short)f2bf(a.z); f[3] = (short)f2bf(a.w);
      f[4] = (short)f2bf(b.x); f[5] = (short)f2bf(b.y);
      f[6] = (short)f2bf(b.z); f[7] = (short)f2bf(b.w);
      Afrag[mt][ks] = f;
    }
  }

  // per-lane -||e||^2/2 for this lane's code in each chunk (static index)
  float enh[NCHUNK];
#pragma unroll
  for (int t = 0; t < NCHUNK; ++t) enh[t] = enormh[t * 64 + ct * 16 + lr];

  float maxv[8];
  int mini[8];
#pragma unroll
  for (int i = 0; i < 8; ++i) { maxv[i] = -INFINITY; mini[i] = 0; }

#pragma unroll
  for (int t = 0; t < NCHUNK; ++t) {
    __syncthreads();  // drains vmcnt -> chunk t resident in Bb[t&1]
    if (t + 1 < NCHUNK) {  // issue chunk t+1 into the other buffer
      const char* src =
          reinterpret_cast<const char*>(Ef) + (size_t)(t + 1) * CHUNK_BYTES;
      char* dst = Bb[(t + 1) & 1];
#pragma unroll
      for (int i = 0; i < 4; ++i) {
        const int o = i * 8192 + tid * 16;
        __builtin_amdgcn_global_load_lds(
            (const __attribute__((address_space(1))) unsigned int*)(src + o),
            (__attribute__((address_space(3))) unsigned int*)(dst + o), 16, 0,
            0);
      }
    }
    const float e = enh[t];
    f32x4 acc[2];
#pragma unroll
    for (int mt = 0; mt < 2; ++mt) {
      acc[mt][0] = e; acc[mt][1] = e; acc[mt][2] = e; acc[mt][3] = e;
    }
#pragma unroll
    for (int ks = 0; ks < 8; ++ks) {
      const bf16x8 bf = *reinterpret_cast<const bf16x8*>(
          &Bb[t & 1][ct * 8192 + ks * 1024 + lane * 16]);
#pragma unroll
      for (int mt = 0; mt < 2; ++mt)
        acc[mt] = __builtin_amdgcn_mfma_f32_16x16x32_bf16(Afrag[mt][ks], bf,
                                                          acc[mt], 0, 0, 0);
    }
    const int code = t * 64 + ct * 16 + lr;
#pragma unroll
    for (int mt = 0; mt < 2; ++mt)
#pragma unroll
      for (int r = 0; r < 4; ++r) {
        const float s = acc[mt][r];
        const int ri = mt * 4 + r;  // row g*32 + mt*16 + lk*4 + r
        if (s > maxv[ri]) { maxv[ri] = s; mini[ri] = code; }
      }
  }

  // reduce across the 16 code-lanes (lr); max score, tie -> lower code
#pragma unroll
  for (int off = 1; off < 16; off <<= 1) {
#pragma unroll
    for (int ri = 0; ri < 8; ++ri) {
      const float ov = __shfl_xor(maxv[ri], off);
      const int oi = __shfl_xor(mini[ri], off);
      if (ov > maxv[ri] || (ov == maxv[ri] && oi < mini[ri])) {
        maxv[ri] = ov; mini[ri] = oi;
      }
    }
  }
  if (lr == 0) {
#pragma unroll
    for (int mt = 0; mt < 2; ++mt)
#pragma unroll
      for (int r = 0; r < 4; ++r) {
        fval_s[ct][g * 32 + mt * 16 + lk * 4 + r] = maxv[mt * 4 + r];
        fidx_s[ct][g * 32 + mt * 16 + lk * 4 + r] = mini[mt * 4 + r];
      }
  }
  __syncthreads();
  if (tid < BM) {
    float bv = fval_s[0][tid];
    int bi = fidx_s[0][tid];
#pragma unroll
    for (int c = 1; c < 4; ++c) {
      const float v = fval_s[c][tid];
      const int i = fidx_s[c][tid];
      if (v > bv || (v == bv && i < bi)) { bv = v; bi = i; }
    }
    idxs[tid] = bi;
  }
  __syncthreads();

  // ---- fused epilogue: gather + STE + loss partial, exact fp32.
  // 8 threads per row, 32 dims each, coalesced float4.
  const int er = tid >> 3;  // row 0..63
  const int eq = tid & 7;
  const int code = idxs[er];
  const float* erow = &E[(size_t)code * DIM];
  const float* xrow = &X[(size_t)(row0 + er) * DIM];
  float* orow = &outq[(size_t)(row0 + er) * DIM];
  float lsum = 0.0f;
#pragma unroll
  for (int j = 0; j < 8; ++j) {
    const int d = j * 32 + eq * 4;
    const float4 e = *reinterpret_cast<const float4*>(&erow[d]);
    const float4 x = *reinterpret_cast<const float4*>(&xrow[d]);
    const float dx0 = e.x - x.x, dx1 = e.y - x.y;
    const float dx2 = e.z - x.z, dx3 = e.w - x.w;
    float4 o;
    o.x = x.x + dx0; o.y = x.y + dx1; o.z = x.z + dx2; o.w = x.w + dx3;
    *reinterpret_cast<float4*>(&orow[d]) = o;
    lsum += dx0 * dx0 + dx1 * dx1 + dx2 * dx2 + dx3 * dx3;
  }
#pragma unroll
  for (int off = 32; off >= 1; off >>= 1) lsum += __shfl_down(lsum, off);
  if (lane == 0) lred[w] = lsum;
  __syncthreads();
  if (tid == 0) {
    float s = 0.0f;
#pragma unroll
    for (int i = 0; i < 8; ++i) s += lred[i];
    partials[blockIdx.x] = s;
  }
}

// ---------------------------------------------------------------------------
// Deterministic loss reduction
// ---------------------------------------------------------------------------
__global__ __launch_bounds__(256) void vq_finalize_kernel(
    const float* __restrict__ partials, float* __restrict__ out_loss,
    int nparts, float inv_count) {
  const int tid = threadIdx.x;
  float s = 0.0f;
  for (int i = tid; i < nparts; i += 256) s += partials[i];
#pragma unroll
  for (int off = 32; off >= 1; off >>= 1) s += __shfl_down(s, off);
  __shared__ float w[4];
  if ((tid & 63) == 0) w[tid >> 6] = s;
  __syncthreads();
  if (tid == 0) {
    const float m = (w[0] + w[1] + w[2] + w[3]) * inv_count;
    out_loss[0] = m + 0.25f * m;  // q_latent + commitment * e_latent
  }
}

extern "C" void kernel_launch(void* const* d_in, const int* in_sizes, int n_in,
                              void* d_out, int out_size, void* d_ws,
                              size_t ws_size, hipStream_t stream) {
  const float* X = (const float*)d_in[0];  // [16,4096,256] fp32
  const float* E = (const float*)d_in[1];  // [1024,256] fp32
  float* out = (float*)d_out;              // [0]=loss, [1..]=quantized

  char* ws = (char*)d_ws;
  float* enormh = (float*)ws;                              // @0KB
  float* partials = (float*)(ws + 16 * 1024);              // @16KB
  unsigned short* Ef = (unsigned short*)(ws + 32 * 1024);  // @32KB (512KB)

  const int nrows = in_sizes[0] / DIM;  // 65536
  const int nb_main = nrows / BM;       // 1024

  vq_prep_kernel<<<KCODES, 64, 0, stream>>>(E, enormh, Ef);
  vq_fused_kernel<<<nb_main, 512, 0, stream>>>(X, E, Ef, enormh, out + 1,
                                               partials);
  vq_finalize_kernel<<<1, 256, 0, stream>>>(partials, out, nb_main,
                                            1.0f / (float)in_sizes[0]);
}